// Round 1
// 113.759 us; speedup vs baseline: 1.0514x; 1.0514x over previous
//
#include <hip/hip_runtime.h>

typedef short bf16x8 __attribute__((ext_vector_type(8)));
typedef float f32x4 __attribute__((ext_vector_type(4)));

#define D 128
#define NROW 98304          // 3 groups * 64 mc * 512 rows
#define X_ELEMS ((size_t)NROW * D)          // bf16 elements in ws
#define NGEMM 512                           // strip blocks (dBA+dBC only)
#define NBLK 576                            // + 64 AC column-sum blocks
#define INV_COUNT 5.9604644775390625e-08f   // 1 / (64*512*512)

typedef __attribute__((address_space(3))) void  as3_void;
typedef const __attribute__((address_space(1))) void as1_cvoid;

__device__ __forceinline__ void gl2lds16(const void* g, void* l) {
    __builtin_amdgcn_global_load_lds((as1_cvoid*)g, (as3_void*)l, 16, 0, 0);
}

__device__ __forceinline__ unsigned short f2bf(float f) {
    unsigned u = __float_as_uint(f);
    u += 0x7FFFu + ((u >> 16) & 1u);        // round-to-nearest-even
    return (unsigned short)(u >> 16);
}
__device__ __forceinline__ float bf2f(unsigned short h) {
    return __uint_as_float(((unsigned)h) << 16);
}

// 8 rows per block; 32 threads per row: float4 loads, 8B bf16 store,
// width-32 shuffle reduce for sum(x_bf16^2).  (unchanged)
__global__ __launch_bounds__(256) void prep_kernel(
    const float* __restrict__ mu, const float* __restrict__ sigma,
    const float* __restrict__ epsA, const float* __restrict__ epsB,
    const float* __restrict__ epsC,
    unsigned short* __restrict__ Xb, float* __restrict__ sumsq)
{
    int t = threadIdx.x;
    int row  = blockIdx.x * 8 + (t >> 5);   // 0..NROW-1
    int ci   = t & 31;                      // float4 index within row
    int n  = row & 511;
    int gm = row >> 9;        // g*64 + m
    int g  = gm >> 6;
    int m  = gm & 63;
    const float* eps = (g == 0) ? epsA : (g == 1) ? epsB : epsC;
    float4 e = ((const float4*)(eps + ((size_t)m * 512 + n) * D))[ci];
    float4 u = ((const float4*)(mu    + ((size_t)(g * 512 + n)) * D))[ci];
    float4 s = ((const float4*)(sigma + ((size_t)(g * 512 + n)) * D))[ci];
    unsigned short b0 = f2bf(fmaf(s.x, e.x, u.x));
    unsigned short b1 = f2bf(fmaf(s.y, e.y, u.y));
    unsigned short b2 = f2bf(fmaf(s.z, e.z, u.z));
    unsigned short b3 = f2bf(fmaf(s.w, e.w, u.w));
    float f0 = bf2f(b0), f1 = bf2f(b1), f2 = bf2f(b2), f3 = bf2f(b3);
    float ss = f0 * f0 + f1 * f1 + f2 * f2 + f3 * f3;
    uint2 packed;
    packed.x = (unsigned)b0 | ((unsigned)b1 << 16);
    packed.y = (unsigned)b2 | ((unsigned)b3 << 16);
    ((uint2*)(Xb + (size_t)row * D))[ci] = packed;
    #pragma unroll
    for (int o = 16; o > 0; o >>= 1) ss += __shfl_down(ss, o, 32);
    if (ci == 0) sumsq[row] = ss;
}

// GEMM strip blocks (bx < 512): one block = 128x512 strip of one (dist,m)
// slice. dist in {BA, BC} only (x side is always group B). A tile (128xK128)
// staged once and cached in registers; B streamed through a double-buffered
// 16 KB half-K chunk pipeline (8 chunks, prefetch-then-compute).
// AC-sum blocks (bx >= 512): per-m column sums of X_A / X_C + dot + sumsq
// partial -> pos term via  sum d2 = 512*sum|x|^2 + 512*sum|y|^2 - 2<SA,SC>.
__global__ __launch_bounds__(256, 2) void dist_kernel(
    const unsigned short* __restrict__ Xb, const float* __restrict__ sumsq,
    float* __restrict__ pslots)
{
    __shared__ unsigned short As[2][128 * 64];   // 32 KB, full-K A (2 halves)
    __shared__ unsigned short Bs[2][128 * 64];   // 32 KB, B chunk double-buffer
    __shared__ float ssx_s[128];
    __shared__ float ssy_s[512];
    __shared__ float red[4];

    const int bx = blockIdx.x;
    const int t  = threadIdx.x;
    const int wave = t >> 6, lane = t & 63;

    if (bx >= NGEMM) {
        // ---------- AC column-sum block: m = bx - 512 ----------
        const int m = bx - NGEMM;
        float* fs = (float*)As;                 // 16 x 128 f32 scratch (8 KB)
        const int d8 = t & 15;                  // bf16x8 column chunk
        const int rg = t >> 4;                  // 16 row-groups x 32 rows
        float S_A = 0.f, dotp = 0.f;
        #pragma unroll
        for (int pass = 0; pass < 2; ++pass) {
            const size_t rowbase = ((size_t)(pass == 0 ? m : 128 + m)) * 512;
            float a8[8] = {};
            for (int r = 0; r < 32; ++r) {
                const unsigned short* p = Xb + (rowbase + rg * 32 + r) * D + d8 * 8;
                bf16x8 v = *(const bf16x8*)p;
                #pragma unroll
                for (int jj = 0; jj < 8; ++jj) a8[jj] += bf2f((unsigned short)v[jj]);
            }
            __syncthreads();
            #pragma unroll
            for (int jj = 0; jj < 8; ++jj) fs[rg * 128 + d8 * 8 + jj] = a8[jj];
            __syncthreads();
            if (t < 128) {
                float s = 0.f;
                #pragma unroll
                for (int g2 = 0; g2 < 16; ++g2) s += fs[g2 * 128 + t];
                if (pass == 0) S_A = s; else dotp = S_A * s;
            }
        }
        float ssum = sumsq[(size_t)m * 512 + t] + sumsq[(size_t)m * 512 + 256 + t]
                   + sumsq[((size_t)(128 + m)) * 512 + t]
                   + sumsq[((size_t)(128 + m)) * 512 + 256 + t];
        float val = fmaf(512.f, ssum, -2.f * dotp);
        #pragma unroll
        for (int o = 32; o > 0; o >>= 1) val += __shfl_down(val, o, 64);
        if (lane == 0) red[wave] = val;
        __syncthreads();
        if (t == 0) pslots[bx] = red[0] + red[1] + red[2] + red[3];
        return;
    }

    // ---------- GEMM strip block ----------
    const int xcd = bx & 7;
    const int idx = bx >> 3;                  // 0..63
    const int tn  = idx & 3;                  // A row-strip within slice
    const int dl  = (idx >> 2) & 1;           // 0 -> dBA, 1 -> dBC
    const int mh  = idx >> 3;                 // 0..7
    const int m   = xcd + mh * 8;             // m % 8 == xcd  (L2 locality)
    const int gy  = dl ? 2 : 0;               // y group: A or C; x is always B(1)

    const char* Xa = (const char*)(Xb + (((size_t)(64 + m)) * 512 + tn * 128) * D);
    const char* Xc = (const char*)(Xb + (((size_t)(gy * 64 + m)) * 512) * D);
    const float* ssx = sumsq + ((size_t)(64 + m)) * 512 + tn * 128;
    const float* ssy = sumsq + ((size_t)(gy * 64 + m)) * 512;

    const int wr = (wave >> 1) * 64;          // wave's 64x64 quadrant rows
    const int wc = (wave & 1) * 64;           // (within the 128-wide tile)
    const int l15 = lane & 15, quad = lane >> 4;

    // staging lane map: 8 rows x 8 granules per 1 KB instr; XOR pre-swizzle
    // of the GLOBAL granule so LDS stays linear (proven 0-conflict layout).
    const int dr8 = lane >> 3, g8 = lane & 7;
    const int voff = dr8 * 256 + ((g8 ^ dr8) * 16);

    // prologue: stage full A (both K halves) + B chunk0 + sumsq rows
    #pragma unroll
    for (int i = 0; i < 4; i++) {
        const int r0 = wave * 32 + i * 8;
        gl2lds16(Xa + r0 * 256 + voff,       &As[0][r0 * 64]);
        gl2lds16(Xa + r0 * 256 + 128 + voff, &As[1][r0 * 64]);
        gl2lds16(Xc + r0 * 256 + voff,       &Bs[0][r0 * 64]);
    }
    if (t < 128) ssx_s[t] = ssx[t];
    ssy_s[t] = ssy[t];
    ssy_s[t + 256] = ssy[t + 256];
    __syncthreads();

    // cache the wave's entire A operand (64 rows x K=128) in registers
    bf16x8 aF[2][2][4];
    #pragma unroll
    for (int h = 0; h < 2; h++)
        #pragma unroll
        for (int ks = 0; ks < 2; ks++)
            #pragma unroll
            for (int fr = 0; fr < 4; fr++)
                aF[h][ks][fr] = *(bf16x8*)&As[h][(wr + fr * 16 + l15) * 64 +
                                                (((ks * 4 + quad) ^ (l15 & 7)) * 8)];

    f32x4 acc[4][4] = {};
    float lsum = 0.f;

    #pragma unroll
    for (int c = 0; c < 8; ++c) {             // chunk = (tk = c>>1, h = c&1)
        const int tk = c >> 1, h = c & 1;
        if (c < 7) {                          // prefetch next B chunk
            const int cn = c + 1, tkn = cn >> 1, hn = cn & 1;
            #pragma unroll
            for (int i = 0; i < 4; i++) {
                const int r0 = wave * 32 + i * 8;
                gl2lds16(Xc + ((size_t)(tkn * 128 + r0)) * 256 + hn * 128 + voff,
                         &Bs[cn & 1][r0 * 64]);
            }
        }
        bf16x8 b[2][4];
        #pragma unroll
        for (int ks = 0; ks < 2; ks++)
            #pragma unroll
            for (int fc = 0; fc < 4; fc++)
                b[ks][fc] = *(bf16x8*)&Bs[c & 1][(wc + fc * 16 + l15) * 64 +
                                                 (((ks * 4 + quad) ^ (l15 & 7)) * 8)];
        #pragma unroll
        for (int ks = 0; ks < 2; ks++)
            #pragma unroll
            for (int fr = 0; fr < 4; fr++)
                #pragma unroll
                for (int fc = 0; fc < 4; fc++)
                    acc[fr][fc] = __builtin_amdgcn_mfma_f32_16x16x32_bf16(
                        aF[h][ks][fr], b[ks][fc], acc[fr][fc], 0, 0, 0);

        if (h == 1) {
            // epilogue for tile tk; C layout: col=lane&15, row=quad*4+i
            #pragma unroll
            for (int fc = 0; fc < 4; fc++) {
                float y2 = ssy_s[tk * 128 + wc + fc * 16 + l15];
                #pragma unroll
                for (int fr = 0; fr < 4; fr++) {
                    float d2v[4];
                    #pragma unroll
                    for (int i = 0; i < 4; i++) {
                        float x2 = ssx_s[wr + fr * 16 + quad * 4 + i];
                        d2v[i] = fmaf(-2.f, acc[fr][fc][i], x2 + y2);
                    }
                    float mn = fminf(fminf(d2v[0], d2v[1]), fminf(d2v[2], d2v[3]));
                    if (__any(mn < 4.f)) {    // relu(M-d) nonzero is rare
                        #pragma unroll
                        for (int i = 0; i < 4; i++) {
                            if (d2v[i] < 4.f) {
                                float td = 2.f - sqrtf(fmaxf(d2v[i], 1e-12f));
                                lsum += td * td;
                            }
                        }
                    }
                    #pragma unroll
                    for (int i = 0; i < 4; i++) acc[fr][fc][i] = 0.f;
                }
            }
        }
        __syncthreads();
    }

    #pragma unroll
    for (int o = 32; o > 0; o >>= 1) lsum += __shfl_down(lsum, o, 64);
    if (lane == 0) red[wave] = lsum;
    __syncthreads();
    if (t == 0)
        pslots[bx] = red[0] + red[1] + red[2] + red[3];
}

// Final reduction: 1 block, 256 threads over 576 partials -> out[0].
__global__ __launch_bounds__(256) void reduce_kernel(
    const float* __restrict__ pslots, float* __restrict__ out)
{
    const int t = threadIdx.x;
    float s = pslots[t] + pslots[t + 256];
    if (t < 64) s += pslots[t + 512];
    #pragma unroll
    for (int o = 32; o > 0; o >>= 1) s += __shfl_down(s, o, 64);
    __shared__ float red[4];
    const int wave = t >> 6, lane = t & 63;
    if (lane == 0) red[wave] = s;
    __syncthreads();
    if (t == 0) out[0] = (red[0] + red[1] + red[2] + red[3]) * INV_COUNT;
}

extern "C" void kernel_launch(void* const* d_in, const int* in_sizes, int n_in,
                              void* d_out, int out_size, void* d_ws, size_t ws_size,
                              hipStream_t stream) {
    const float* mu    = (const float*)d_in[0];
    const float* sigma = (const float*)d_in[1];
    const float* epsA  = (const float*)d_in[2];
    const float* epsB  = (const float*)d_in[3];
    const float* epsC  = (const float*)d_in[4];
    float* out = (float*)d_out;

    unsigned short* Xb = (unsigned short*)d_ws;              // 25.17 MB bf16
    float* sumsq  = (float*)((char*)d_ws + X_ELEMS * sizeof(unsigned short)); // 0.39 MB
    float* pslots = sumsq + NROW;                            // 2.3 KB partials

    prep_kernel<<<NROW / 8, 256, 0, stream>>>(mu, sigma, epsA, epsB, epsC, Xb, sumsq);

    dist_kernel<<<NBLK, 256, 0, stream>>>(Xb, sumsq, pslots);

    reduce_kernel<<<1, 256, 0, stream>>>(pslots, out);
}